// Round 7
// baseline (46918.036 us; speedup 1.0000x reference)
//
#include <hip/hip_runtime.h>

// Persistent-LSTM MI355X — Round 7: hybrid sync (compact-tag detect +
// self-validating tagged data pairs).
// R6 (34.4ms, 4.2us/step) chain: h-store -> drain+barrier -> tag store ->
// tag vis -> detect -> data fetch = 3 serialized L3 latencies + 2 barriers.
// R7 removes one L3 hop and one barrier:
//  - h published as {tag|val} u64 pairs (8 per block, one 64B line) -> data
//    self-validates, so the per-block slot tag is a HINT stored concurrently
//    with data (no producer drain, no second __syncthreads).
//  - consumer speculatively issues its 4 pair loads, THEN polls its 2 compact
//    tag lines (1 load/lane, R6's low-traffic detect), then validates pair
//    tags; refetches only stale pairs (rare - data/tag travel together).
// Critical path ~= max(data vis, tag vis) + detect; fetch overlaps detect.
//
// 256 blocks x 512 threads, 1 block/CU -> all co-resident, spin safe.
// Block b owns units [8b,8b+8); wave wv computes unit j=8b+wv; pairs are
// unit-indexed (= block-major: block b's 8 pairs share one line).
// Wave wv stages pair slice [wv*256,(wv+1)*256) = producer blocks
// [wv*32,wv*32+32) = slot lines 2.

#define H      2048
#define TSTEPS 8192
#define FEAT   128
#define NBLK   256
#define NTHR   512

typedef float vf4 __attribute__((ext_vector_type(4)));
typedef float vf2 __attribute__((ext_vector_type(2)));
typedef unsigned long long u64;
typedef unsigned int u32;

__device__ __forceinline__ float sigm(float xv) {
  return __builtin_amdgcn_rcpf(1.0f + __expf(-xv));
}
__device__ __forceinline__ float tanh_(float xv) {
  return 1.0f - 2.0f * __builtin_amdgcn_rcpf(__expf(2.0f * xv) + 1.0f);
}

__device__ __forceinline__ u64 aload64(const u64* p) {
  return __hip_atomic_load(p, __ATOMIC_RELAXED, __HIP_MEMORY_SCOPE_AGENT);
}
__device__ __forceinline__ u32 aload32(const u32* p) {
  return __hip_atomic_load(p, __ATOMIC_RELAXED, __HIP_MEMORY_SCOPE_AGENT);
}
__device__ __forceinline__ void astore64(u64* p, u64 v) {
  __hip_atomic_store(p, v, __ATOMIC_RELAXED, __HIP_MEMORY_SCOPE_AGENT);
}
__device__ __forceinline__ void astoreu(u32* p, u32 v) {
  __hip_atomic_store(p, v, __ATOMIC_RELAXED, __HIP_MEMORY_SCOPE_AGENT);
}

#define DECLG(g) vf4 w##g##_0, w##g##_1, w##g##_2, w##g##_3, \
                     w##g##_4, w##g##_5, w##g##_6, w##g##_7; \
                 vf2 wih##g; float bias##g; float acc##g;

#define LOADG(g) { \
  const int row_ = (g) * H + j; \
  const float* wr_ = W_hh + (long)row_ * H; \
  w##g##_0 = *(const vf4*)(wr_ + 4*(ln      )); \
  w##g##_1 = *(const vf4*)(wr_ + 4*(ln +  64)); \
  w##g##_2 = *(const vf4*)(wr_ + 4*(ln + 128)); \
  w##g##_3 = *(const vf4*)(wr_ + 4*(ln + 192)); \
  w##g##_4 = *(const vf4*)(wr_ + 4*(ln + 256)); \
  w##g##_5 = *(const vf4*)(wr_ + 4*(ln + 320)); \
  w##g##_6 = *(const vf4*)(wr_ + 4*(ln + 384)); \
  w##g##_7 = *(const vf4*)(wr_ + 4*(ln + 448)); \
  wih##g  = *(const vf2*)(W_ih + (long)row_ * FEAT + 2*ln); \
  bias##g = b_ih[row_] + b_hh[row_]; }

// Opaque pin: weights become non-rematerializable (cannot re-sink into loop).
#define PIN(g) asm volatile("" : \
  "+v"(w##g##_0), "+v"(w##g##_1), "+v"(w##g##_2), "+v"(w##g##_3), \
  "+v"(w##g##_4), "+v"(w##g##_5), "+v"(w##g##_6), "+v"(w##g##_7), \
  "+v"(wih##g), "+v"(bias##g));

#define LDSREAD(k, ldsrow) \
  const vf4 hv##k = *(const vf4*)&(ldsrow)[4*(ln + 64*(k))];

#define FMA_G(g, c) \
  acc##g = __builtin_fmaf(w##g##_##c.x, h4_.x, acc##g); \
  acc##g = __builtin_fmaf(w##g##_##c.y, h4_.y, acc##g); \
  acc##g = __builtin_fmaf(w##g##_##c.z, h4_.z, acc##g); \
  acc##g = __builtin_fmaf(w##g##_##c.w, h4_.w, acc##g);

#define FMA_C(c) { const vf4 h4_ = hv##c; \
  FMA_G(0, c) FMA_G(1, c) FMA_G(2, c) FMA_G(3, c) }

#define REDUCE(g) { float a_ = acc##g; \
  a_ += __shfl_xor(a_, 1);  a_ += __shfl_xor(a_, 2);  a_ += __shfl_xor(a_, 4); \
  a_ += __shfl_xor(a_, 8);  a_ += __shfl_xor(a_, 16); a_ += __shfl_xor(a_, 32); \
  acc##g = a_ + bias##g; }

// Wave-level stage of pairs [wv*256, wv*256+256):
// 1) speculatively issue this lane's 4 pair loads;
// 2) poll the 32 producer-block slots of this slice (lanes 0..31, 1 ea;
//    signed compare -> 0xAA poison inert);
// 3) validate embedded pair tags; refetch stale pairs only (rare);
// 4) deposit 4 h values into LDS.
__device__ __forceinline__ void stage(const u64* __restrict__ buf,
                                      const u32* __restrict__ slots,
                                      int tgt,
                                      float* __restrict__ ldsrow,
                                      int wv, int ln) {
  const int pbase = wv * 256 + 4 * ln;
  const u64* p = buf + pbase;
  u64 a0 = aload64(p + 0);
  u64 a1 = aload64(p + 1);
  u64 a2 = aload64(p + 2);
  u64 a3 = aload64(p + 3);

  {
    const u32* sp = slots + wv * 32 + (ln & 31);
    int v = (int)aload32(sp);
    while (!__all((ln < 32) ? (v >= tgt) : 1)) {
      __builtin_amdgcn_s_sleep(1);
      if ((ln < 32) && (v < tgt)) v = (int)aload32(sp);
    }
  }

  const u32 tg = (u32)tgt;
  while (true) {
    const int ok = ((u32)a0 == tg) & ((u32)a1 == tg) &
                   ((u32)a2 == tg) & ((u32)a3 == tg);
    if (__all(ok)) break;
    __builtin_amdgcn_s_sleep(1);
    if ((u32)a0 != tg) a0 = aload64(p + 0);
    if ((u32)a1 != tg) a1 = aload64(p + 1);
    if ((u32)a2 != tg) a2 = aload64(p + 2);
    if ((u32)a3 != tg) a3 = aload64(p + 3);
  }

  vf4 hv;
  hv.x = __uint_as_float((u32)(a0 >> 32));
  hv.y = __uint_as_float((u32)(a1 >> 32));
  hv.z = __uint_as_float((u32)(a2 >> 32));
  hv.w = __uint_as_float((u32)(a3 >> 32));
  *(vf4*)&ldsrow[pbase] = hv;
}

__global__ __launch_bounds__(NTHR, 2)
void lstm_persist(const float* __restrict__ x,
                  const float* __restrict__ W_ih,
                  const float* __restrict__ W_hh,
                  const float* __restrict__ b_ih,
                  const float* __restrict__ b_hh,
                  const float* __restrict__ W_lin,
                  const float* __restrict__ b_lin,
                  const float* __restrict__ W_out,
                  const float* __restrict__ b_out,
                  float* __restrict__ out,
                  float* __restrict__ ws)
{
  const int tid = threadIdx.x;
  const int b   = blockIdx.x;
  const int wv  = tid >> 6;
  const int ln  = tid & 63;

  u64* buf0  = (u64*)ws;            // {tag|val} pairs, even tags
  u64* buf1  = buf0 + H;            // odd tags (tail: ylin w/ tag TSTEPS+1)
  u32* slots = (u32*)(buf1 + H);    // [256] per-block hint counters (1 KB)

  __shared__ __align__(16) float h_lds[2][H];

  // h_0 = 0: zero parity-0 LDS row
  *(vf4*)&h_lds[0][4 * tid] = (vf4)(0.0f);

  // ---- persistent weights: load then pin ----
  const int j = b * 8 + wv;
  DECLG(0) DECLG(1) DECLG(2) DECLG(3)
  LOADG(0) LOADG(1) LOADG(2) LOADG(3)
  PIN(0) PIN(1) PIN(2) PIN(3)

  __syncthreads();

  float cst = 0.0f;

  #pragma unroll 1
  for (int t = 0; t < TSTEPS; ++t) {
    const vf2 xr = *(const vf2*)(x + (long)t * FEAT + 2 * ln);
    float* ldsrow = h_lds[t & 1];

    if (t > 0)
      stage((t & 1) ? buf1 : buf0, slots, t, ldsrow, wv, ln);
    __syncthreads();   // the ONLY barrier per step

    LDSREAD(0, ldsrow) LDSREAD(1, ldsrow) LDSREAD(2, ldsrow) LDSREAD(3, ldsrow)
    LDSREAD(4, ldsrow) LDSREAD(5, ldsrow) LDSREAD(6, ldsrow) LDSREAD(7, ldsrow)

    acc0 = wih0.x * xr.x + wih0.y * xr.y;
    acc1 = wih1.x * xr.x + wih1.y * xr.y;
    acc2 = wih2.x * xr.x + wih2.y * xr.y;
    acc3 = wih3.x * xr.x + wih3.y * xr.y;

    FMA_C(0) FMA_C(1) FMA_C(2) FMA_C(3)
    FMA_C(4) FMA_C(5) FMA_C(6) FMA_C(7)

    REDUCE(0) REDUCE(1) REDUCE(2) REDUCE(3)

    // gate order [i, f, g, o]
    const float iv = sigm(acc0);
    const float fv = sigm(acc1);
    const float gv = tanh_(acc2);
    const float ov = sigm(acc3);
    cst = fv * cst + iv * gv;
    const float hval = ov * tanh_(cst);

    // publish: tagged pair (self-validating) + hint slot, no drain between
    if (ln == 0) {
      u64* dst = (((t + 1) & 1) ? buf1 : buf0) + j;
      astore64(dst, ((u64)__float_as_uint(hval) << 32) | (u32)(t + 1));
    }
    if (tid == 0)
      astoreu(slots + b, (u32)(t + 1));
  }

  // ---- head phase 1: ylin[j] = b_lin[j] + dot(W_lin[j,:], h_final) ----
  // h_final = h_8192, tag TSTEPS, parity 0.
  {
    float* ldsrow = h_lds[0];
    stage(buf0, slots, TSTEPS, ldsrow, wv, ln);
    __syncthreads();

    float a0 = 0.0f;
    const float* wl = W_lin + (long)j * H;
    #pragma unroll
    for (int k = 0; k < 8; ++k) {
      const vf4 h4 = *(const vf4*)&ldsrow[4 * (ln + 64 * k)];
      const vf4 u  = *(const vf4*)(wl + 4 * (ln + 64 * k));
      a0 += u.x * h4.x + u.y * h4.y + u.z * h4.z + u.w * h4.w;
    }
    a0 += __shfl_xor(a0, 1);  a0 += __shfl_xor(a0, 2);  a0 += __shfl_xor(a0, 4);
    a0 += __shfl_xor(a0, 8);  a0 += __shfl_xor(a0, 16); a0 += __shfl_xor(a0, 32);

    if (ln == 0) {
      const float yv = a0 + b_lin[j];
      astore64(buf1 + j,
               ((u64)__float_as_uint(yv) << 32) | (u32)(TSTEPS + 1));
    }
  }

  // ---- head phase 2: y = ylin @ W_out.T + b_out (block 0, wave 0) ----
  // One-time tail: direct self-validating poll of all 2048 ylin pairs.
  if (b == 0 && wv == 0) {
    u64 pv[32];
    #pragma unroll
    for (int k = 0; k < 32; ++k)
      pv[k] = aload64(buf1 + ln + 64 * k);
    const u32 tg = (u32)(TSTEPS + 1);
    while (true) {
      int ok = 1;
      #pragma unroll
      for (int k = 0; k < 32; ++k)
        ok &= ((u32)pv[k] == tg) ? 1 : 0;
      if (__all(ok)) break;
      __builtin_amdgcn_s_sleep(1);
      #pragma unroll
      for (int k = 0; k < 32; ++k)
        if ((u32)pv[k] != tg)
          pv[k] = aload64(buf1 + ln + 64 * k);
    }
    float p0 = 0.0f, p1 = 0.0f;
    #pragma unroll
    for (int k = 0; k < 32; ++k) {
      const int c = ln + 64 * k;
      const float yv = __uint_as_float((u32)(pv[k] >> 32));
      p0 = __builtin_fmaf(W_out[c],     yv, p0);
      p1 = __builtin_fmaf(W_out[H + c], yv, p1);
    }
    p0 += __shfl_xor(p0, 1);  p0 += __shfl_xor(p0, 2);  p0 += __shfl_xor(p0, 4);
    p0 += __shfl_xor(p0, 8);  p0 += __shfl_xor(p0, 16); p0 += __shfl_xor(p0, 32);
    p1 += __shfl_xor(p1, 1);  p1 += __shfl_xor(p1, 2);  p1 += __shfl_xor(p1, 4);
    p1 += __shfl_xor(p1, 8);  p1 += __shfl_xor(p1, 16); p1 += __shfl_xor(p1, 32);
    if (ln == 0) {
      out[0] = p0 + b_out[0];
      out[1] = p1 + b_out[1];
    }
  }
}

extern "C" void kernel_launch(void* const* d_in, const int* in_sizes, int n_in,
                              void* d_out, int out_size, void* d_ws, size_t ws_size,
                              hipStream_t stream) {
  const float* x     = (const float*)d_in[0];
  const float* W_ih  = (const float*)d_in[1];
  const float* W_hh  = (const float*)d_in[2];
  const float* b_ih  = (const float*)d_in[3];
  const float* b_hh  = (const float*)d_in[4];
  const float* W_lin = (const float*)d_in[5];
  const float* b_lin = (const float*)d_in[6];
  const float* W_out = (const float*)d_in[7];
  const float* b_out = (const float*)d_in[8];

  lstm_persist<<<dim3(NBLK), dim3(NTHR), 0, stream>>>(
      x, W_ih, W_hh, b_ih, b_hh, W_lin, b_lin, W_out, b_out,
      (float*)d_out, (float*)d_ws);
}